// Round 6
// baseline (11.495 us; speedup 1.0000x reference)
//
#include <hip/hip_runtime.h>
#include <hip/hip_bf16.h>
#include <math.h>

// 4-wire quantum circuit, B=262144 — single fused kernel, v6.
//
//   out = | cos(y0) cos(x0) + sin(y0) sin(x0) * g(x1,x2,x3) |
//   g = psi123^T N psi123, N = Re(U00~^dag U11~), reduced to a 27-coef
//   trig tensor over basis (1, cos x_w, sin x_w) per wire.
// Algebra (verified R5): wire 0 never rotated -> U block-diagonal; shared
// tail C12*L5 cancels in N (ops 16..19 dropped); L1|col> is a direct
// product state.
// v6 structure: per-WAVE redundant prep into per-wave LDS slots; phases
// sync via s_waitcnt lgkmcnt(0) (wave-level LDS counter) — zero s_barrier.
// Theta loads + trig live only in the 16-lane prep branch (batch-uniform
// work stays off the per-thread path — R5 lesson).

template<int BIT>
__device__ __forceinline__ void rx8(float (&sr)[8], float (&si)[8], float c, float s) {
    #pragma unroll
    for (int i = 0; i < 8; ++i) {
        if (!(i & (1 << BIT))) {
            const int j = i | (1 << BIT);
            float ar = sr[i], ai = si[i], br = sr[j], bi = si[j];
            sr[i] = c * ar + s * bi;  si[i] = c * ai - s * br;
            sr[j] = c * br + s * ai;  si[j] = c * bi - s * ar;
        }
    }
}

template<int BIT>
__device__ __forceinline__ void ry8(float (&sr)[8], float (&si)[8], float c, float s) {
    #pragma unroll
    for (int i = 0; i < 8; ++i) {
        if (!(i & (1 << BIT))) {
            const int j = i | (1 << BIT);
            float ar = sr[i], ai = si[i], br = sr[j], bi = si[j];
            sr[i] = c * ar - s * br;  si[i] = c * ai - s * bi;
            sr[j] = s * ar + c * br;  si[j] = s * ai + c * bi;
        }
    }
}

template<int BIT>
__device__ __forceinline__ void rz8(float (&sr)[8], float (&si)[8], float c, float s) {
    #pragma unroll
    for (int i = 0; i < 8; ++i) {
        if (!(i & (1 << BIT))) {
            const int j = i | (1 << BIT);
            float ar = sr[i], ai = si[i], br = sr[j], bi = si[j];
            sr[i] = c * ar + s * ai;  si[i] = c * ai - s * ar;
            sr[j] = c * br - s * bi;  si[j] = c * bi + s * br;
        }
    }
}

template<int CB, int TB>
__device__ __forceinline__ void cnot8(float (&sr)[8], float (&si)[8]) {
    #pragma unroll
    for (int i = 0; i < 8; ++i) {
        if ((i & (1 << CB)) && !(i & (1 << TB))) {
            const int j = i | (1 << TB);
            float t;
            t = sr[i]; sr[i] = sr[j]; sr[j] = t;
            t = si[i]; si[i] = si[j]; si[j] = t;
        }
    }
}

__device__ __forceinline__ void tri_transform(float* T, int base, int s) {
    // axis basis change (c^2, cs, s^2) -> (1, cos, sin)
    float x0 = T[base], x1 = T[base + s], x2 = T[base + 2 * s];
    T[base]         = 0.5f * (x0 + x2);
    T[base + s]     = 0.5f * (x0 - x2);
    T[base + 2 * s] = 0.5f * x1;
}

#define WAVE_SYNC() do { \
    asm volatile("s_waitcnt lgkmcnt(0)" ::: "memory"); \
    __builtin_amdgcn_sched_barrier(0); \
} while (0)

__global__ __launch_bounds__(256) void qfused_kernel(
        const float* __restrict__ x,
        const float* __restrict__ y,
        const float* __restrict__ theta,
        float* __restrict__ out,
        int B) {
    __shared__ float Vr[4][2][8][8], Vi[4][2][8][8];  // per-wave slots
    __shared__ float Nm[4][64];
    __shared__ float T[4][27];

    const int t    = threadIdx.x;
    const int wid  = t >> 6;
    const int lane = t & 63;
    const int b    = blockIdx.x * 256 + t;            // B == grid*256 exactly

    // ---- hoisted per-thread loads (latency hides under prep) ----
    const float4 xv = reinterpret_cast<const float4*>(x)[b];
    const float  y0 = y[4 * b];

    // ---- prep phase 0 (lanes 0..15 of EACH wave): evolve U00~/U11~ ----
    if (lane < 16) {
        float tC[12], tS[12];
        #pragma unroll
        for (int i = 0; i < 12; ++i) {
            const int idx = i + (i / 3);              // 0,1,2, 4,5,6, 8,9,10, 12,13,14
            __sincosf(0.5f * theta[idx], &tS[i], &tC[i]);
        }
        const int col = lane & 7, blk = lane >> 3;
        const int c0 = col & 1, c1 = (col >> 1) & 1, c2 = (col >> 2) & 1;
        float sr[8], si[8];
        // direct init: [X1 if blk] * RZ1(th2) RY2(th1) RX3(th0) |col>
        {
            const float pr = tC[2];
            const float pi = c2 ? tS[2] : -tS[2];
            const int r2s = (c2 ^ blk) << 2;
            const int r2o = r2s ^ 4;
            #pragma unroll
            for (int i = 0; i < 8; ++i) { sr[i] = 0.0f; si[i] = 0.0f; }
            #pragma unroll
            for (int r1 = 0; r1 < 2; ++r1) {
                const float g = (r1 == c1) ? tC[1] : (r1 ? tS[1] : -tS[1]);
                #pragma unroll
                for (int r0 = 0; r0 < 2; ++r0) {
                    const int r = r2s | (r1 << 1) | r0;
                    if (r0 == c0) { sr[r] = pr * g * tC[0]; si[r] = pi * g * tC[0]; }
                    else          { sr[r] = pi * g * tS[0]; si[r] = -pr * g * tS[0]; }
                }
            }
            (void)r2o;
        }
        rx8<0>(sr, si, tC[3], tS[3]);    // L2
        ry8<1>(sr, si, tC[4], tS[4]);
        rz8<2>(sr, si, tC[5], tS[5]);
        cnot8<2, 1>(sr, si);             // CNOT(1,2)
        rx8<0>(sr, si, tC[6], tS[6]);    // L3
        ry8<1>(sr, si, tC[7], tS[7]);
        rz8<2>(sr, si, tC[8], tS[8]);
        cnot8<1, 0>(sr, si);             // CNOT(2,3)
        rx8<0>(sr, si, tC[9], tS[9]);    // L4
        ry8<1>(sr, si, tC[10], tS[10]);
        rz8<2>(sr, si, tC[11], tS[11]);
        const int rxr = blk << 2;        // trailing X1 on U11~ = row permute
        #pragma unroll
        for (int k = 0; k < 8; ++k) {
            Vr[wid][blk][k ^ rxr][col] = sr[k];
            Vi[wid][blk][k ^ rxr][col] = si[k];
        }
    }
    WAVE_SYNC();

    // ---- phase A (all 64 lanes): N_ij = sum_k Re(conj(U00~[k,i]) U11~[k,j]) ----
    {
        const int i = lane >> 3, j = lane & 7;
        float a = 0.0f;
        #pragma unroll
        for (int k = 0; k < 8; ++k) {
            a = fmaf(Vr[wid][0][k][i], Vr[wid][1][k][j], a);
            a = fmaf(Vi[wid][0][k][i], Vi[wid][1][k][j], a);
        }
        Nm[wid][lane] = a;
    }
    WAVE_SYNC();

    // ---- phase B (lanes 0..26): gather into 3^3 tensor ----
    if (lane < 27) {
        const int d1 = lane / 9, d2 = (lane / 3) % 3, d3 = lane % 3;
        const int ones = ((d1 == 1) << 2) | ((d2 == 1) << 1) | (d3 == 1);
        const int twos = ((d1 == 2) << 2) | ((d2 == 2) << 1) | (d3 == 2);
        float a = 0.0f;
        #pragma unroll
        for (int c = 0; c < 8; ++c) {
            if (c & ~ones) continue;
            a += Nm[wid][(twos | c) * 8 + (twos | (ones & ~c))];
        }
        T[wid][lane] = a;
    }
    WAVE_SYNC();

    // ---- phase C (lanes 0..8): basis transform along the 3 axes ----
    if (lane < 9) tri_transform(&T[wid][0], lane, 9);
    WAVE_SYNC();
    if (lane < 9) tri_transform(&T[wid][0], 9 * (lane / 3) + (lane % 3), 3);
    WAVE_SYNC();
    if (lane < 9) tri_transform(&T[wid][0], 3 * lane, 1);
    WAVE_SYNC();

    // ---- eval (all threads) ----
    const float cx0 = __cosf(xv.x), sx0 = __sinf(xv.x);
    const float cx1 = __cosf(xv.y), sx1 = __sinf(xv.y);
    const float cx2 = __cosf(xv.z), sx2 = __sinf(xv.z);
    const float cx3 = __cosf(xv.w), sx3 = __sinf(xv.w);
    const float cy  = __cosf(y0),   sy  = __sinf(y0);

    const float* Tw = &T[wid][0];
    float r3[9];
    #pragma unroll
    for (int m = 0; m < 9; ++m)
        r3[m] = fmaf(sx3, Tw[3 * m + 2], fmaf(cx3, Tw[3 * m + 1], Tw[3 * m]));
    float r2[3];
    #pragma unroll
    for (int m = 0; m < 3; ++m)
        r2[m] = fmaf(sx2, r3[3 * m + 2], fmaf(cx2, r3[3 * m + 1], r3[3 * m]));
    const float g = fmaf(sx1, r2[2], fmaf(cx1, r2[1], r2[0]));

    out[b] = fabsf(fmaf(cy, cx0, sy * sx0 * g));
}

extern "C" void kernel_launch(void* const* d_in, const int* in_sizes, int n_in,
                              void* d_out, int out_size, void* d_ws, size_t ws_size,
                              hipStream_t stream) {
    const float* x     = (const float*)d_in[0];
    const float* y     = (const float*)d_in[1];
    const float* theta = (const float*)d_in[2];
    float* out = (float*)d_out;

    int B = out_size;  // 262144 = 1024 * 256
    int block = 256;
    int grid = B / block;
    qfused_kernel<<<grid, block, 0, stream>>>(x, y, theta, out, B);
}

// Round 7
// 9.765 us; speedup vs baseline: 1.1772x; 1.1772x over previous
//
#include <hip/hip_runtime.h>
#include <hip/hip_bf16.h>
#include <math.h>

// 4-wire quantum circuit, B=262144 — single fused kernel, v7.
// Structure = R4 (best measured: single 16-lane prep branch + __syncthreads),
// algebra = v5 (wire-0 block-diagonal; shared tail cancels -> 9 rotations;
// L1|col> = direct product state; 12 theta sincos, all inside the branch).
//
//   out = | cos(y0) cos(x0) + sin(y0) sin(x0) * g(x1,x2,x3) |
//   g = psi123^T N psi123, N = Re(U00~^dag U11~), reduced to a 27-coef
//   trig tensor over basis (1, cos x_w, sin x_w) per wire.

template<int BIT>
__device__ __forceinline__ void rx8(float (&sr)[8], float (&si)[8], float c, float s) {
    #pragma unroll
    for (int i = 0; i < 8; ++i) {
        if (!(i & (1 << BIT))) {
            const int j = i | (1 << BIT);
            float ar = sr[i], ai = si[i], br = sr[j], bi = si[j];
            sr[i] = c * ar + s * bi;  si[i] = c * ai - s * br;
            sr[j] = c * br + s * ai;  si[j] = c * bi - s * ar;
        }
    }
}

template<int BIT>
__device__ __forceinline__ void ry8(float (&sr)[8], float (&si)[8], float c, float s) {
    #pragma unroll
    for (int i = 0; i < 8; ++i) {
        if (!(i & (1 << BIT))) {
            const int j = i | (1 << BIT);
            float ar = sr[i], ai = si[i], br = sr[j], bi = si[j];
            sr[i] = c * ar - s * br;  si[i] = c * ai - s * bi;
            sr[j] = s * ar + c * br;  si[j] = s * ai + c * bi;
        }
    }
}

template<int BIT>
__device__ __forceinline__ void rz8(float (&sr)[8], float (&si)[8], float c, float s) {
    #pragma unroll
    for (int i = 0; i < 8; ++i) {
        if (!(i & (1 << BIT))) {
            const int j = i | (1 << BIT);
            float ar = sr[i], ai = si[i], br = sr[j], bi = si[j];
            sr[i] = c * ar + s * ai;  si[i] = c * ai - s * ar;
            sr[j] = c * br - s * bi;  si[j] = c * bi + s * br;
        }
    }
}

template<int CB, int TB>
__device__ __forceinline__ void cnot8(float (&sr)[8], float (&si)[8]) {
    #pragma unroll
    for (int i = 0; i < 8; ++i) {
        if ((i & (1 << CB)) && !(i & (1 << TB))) {
            const int j = i | (1 << TB);
            float t;
            t = sr[i]; sr[i] = sr[j]; sr[j] = t;
            t = si[i]; si[i] = si[j]; si[j] = t;
        }
    }
}

__device__ __forceinline__ void tri_transform(volatile float* T, int base, int s) {
    // axis basis change (c^2, cs, s^2) -> (1, cos, sin)
    float x0 = T[base], x1 = T[base + s], x2 = T[base + 2 * s];
    T[base]         = 0.5f * (x0 + x2);
    T[base + s]     = 0.5f * (x0 - x2);
    T[base + 2 * s] = 0.5f * x1;
}

__global__ __launch_bounds__(256) void qfused_kernel(
        const float* __restrict__ x,
        const float* __restrict__ y,
        const float* __restrict__ theta,
        float* __restrict__ out,
        int B) {
    __shared__ float Vr[2][8][8], Vi[2][8][8];   // [blk][row k][col]
    __shared__ float Nm[64];                     // Re(U00~^dag U11~)
    __shared__ float T[27];                      // trig tensor

    const int t = threadIdx.x;
    const int b = blockIdx.x * 256 + t;          // B == grid*256 exactly

    // ---- hoisted per-thread loads (latency hides under prep) ----
    const float4 xv = reinterpret_cast<const float4*>(x)[b];
    const float  y0 = y[4 * b];

    // ---- Phase 0 (16 lanes): evolve 8 columns of U00~ / U11~ ----
    if (t < 16) {
        float tC[12], tS[12];
        #pragma unroll
        for (int i = 0; i < 12; ++i) {
            const int idx = i + (i / 3);         // 0,1,2, 4,5,6, 8,9,10, 12,13,14
            __sincosf(0.5f * theta[idx], &tS[i], &tC[i]);
        }
        const int col = t & 7, blk = t >> 3;
        const int c0 = col & 1, c1 = (col >> 1) & 1, c2 = (col >> 2) & 1;
        float sr[8], si[8];
        // direct init: [X1 if blk] * RZ1(th2) RY2(th1) RX3(th0) |col>
        {
            const float pr = tC[2];
            const float pi = c2 ? tS[2] : -tS[2];
            const int r2s = (c2 ^ blk) << 2;
            #pragma unroll
            for (int i = 0; i < 8; ++i) { sr[i] = 0.0f; si[i] = 0.0f; }
            #pragma unroll
            for (int r1 = 0; r1 < 2; ++r1) {
                const float g = (r1 == c1) ? tC[1] : (r1 ? tS[1] : -tS[1]);
                #pragma unroll
                for (int r0 = 0; r0 < 2; ++r0) {
                    const int r = r2s | (r1 << 1) | r0;
                    if (r0 == c0) { sr[r] = pr * g * tC[0]; si[r] = pi * g * tC[0]; }
                    else          { sr[r] = pi * g * tS[0]; si[r] = -pr * g * tS[0]; }
                }
            }
        }
        rx8<0>(sr, si, tC[3], tS[3]);    // L2
        ry8<1>(sr, si, tC[4], tS[4]);
        rz8<2>(sr, si, tC[5], tS[5]);
        cnot8<2, 1>(sr, si);             // CNOT(1,2)
        rx8<0>(sr, si, tC[6], tS[6]);    // L3
        ry8<1>(sr, si, tC[7], tS[7]);
        rz8<2>(sr, si, tC[8], tS[8]);
        cnot8<1, 0>(sr, si);             // CNOT(2,3)
        rx8<0>(sr, si, tC[9], tS[9]);    // L4
        ry8<1>(sr, si, tC[10], tS[10]);
        rz8<2>(sr, si, tC[11], tS[11]);
        const int rxr = blk << 2;        // trailing X1 on U11~ = row permute
        #pragma unroll
        for (int k = 0; k < 8; ++k) {
            Vr[blk][k ^ rxr][col] = sr[k];
            Vi[blk][k ^ rxr][col] = si[k];
        }
    }
    __syncthreads();

    // ---- Phase A: N_ij = sum_k Re(conj(U00~[k,i]) * U11~[k,j]) ----
    if (t < 64) {
        const int i = t >> 3, j = t & 7;
        float a = 0.0f;
        #pragma unroll
        for (int k = 0; k < 8; ++k) {
            a = fmaf(Vr[0][k][i], Vr[1][k][j], a);
            a = fmaf(Vi[0][k][i], Vi[1][k][j], a);
        }
        Nm[t] = a;
    }
    __syncthreads();

    // ---- Phase B: gather into 3^3 tensor ----
    if (t < 27) {
        const int d1 = t / 9, d2 = (t / 3) % 3, d3 = t % 3;
        const int ones = ((d1 == 1) << 2) | ((d2 == 1) << 1) | (d3 == 1);
        const int twos = ((d1 == 2) << 2) | ((d2 == 2) << 1) | (d3 == 2);
        float a = 0.0f;
        #pragma unroll
        for (int c = 0; c < 8; ++c) {
            if (c & ~ones) continue;
            a += Nm[(twos | c) * 8 + (twos | (ones & ~c))];
        }
        T[t] = a;
    }
    __syncthreads();

    // ---- Phase C: basis transform along the 3 axes ----
    if (t < 9) tri_transform(T, t, 9);
    __syncthreads();
    if (t < 9) tri_transform(T, 9 * (t / 3) + (t % 3), 3);
    __syncthreads();
    if (t < 9) tri_transform(T, 3 * t, 1);
    __syncthreads();

    // ---- Eval: one batch element per thread ----
    const float cx0 = __cosf(xv.x), sx0 = __sinf(xv.x);
    const float cx1 = __cosf(xv.y), sx1 = __sinf(xv.y);
    const float cx2 = __cosf(xv.z), sx2 = __sinf(xv.z);
    const float cx3 = __cosf(xv.w), sx3 = __sinf(xv.w);
    const float cy  = __cosf(y0),   sy  = __sinf(y0);

    float r3[9];
    #pragma unroll
    for (int m = 0; m < 9; ++m)
        r3[m] = fmaf(sx3, T[3 * m + 2], fmaf(cx3, T[3 * m + 1], T[3 * m]));
    float r2[3];
    #pragma unroll
    for (int m = 0; m < 3; ++m)
        r2[m] = fmaf(sx2, r3[3 * m + 2], fmaf(cx2, r3[3 * m + 1], r3[3 * m]));
    const float g = fmaf(sx1, r2[2], fmaf(cx1, r2[1], r2[0]));

    out[b] = fabsf(fmaf(cy, cx0, sy * sx0 * g));
}

extern "C" void kernel_launch(void* const* d_in, const int* in_sizes, int n_in,
                              void* d_out, int out_size, void* d_ws, size_t ws_size,
                              hipStream_t stream) {
    const float* x     = (const float*)d_in[0];
    const float* y     = (const float*)d_in[1];
    const float* theta = (const float*)d_in[2];
    float* out = (float*)d_out;

    int B = out_size;  // 262144 = 1024 * 256
    int block = 256;
    int grid = B / block;
    qfused_kernel<<<grid, block, 0, stream>>>(x, y, theta, out, B);
}